// Round 2
// baseline (507.884 us; speedup 1.0000x reference)
//
#include <hip/hip_runtime.h>
#include <hip/hip_bf16.h>

typedef __attribute__((ext_vector_type(8))) short short8;
typedef __attribute__((ext_vector_type(4))) float floatx4;
typedef __attribute__((ext_vector_type(4))) unsigned short ushort4v;

#define NQ 512
#define NH 100000
#define DM 256
#define BH 64
#define BQ 64

#define MFMA_BF16(a, b, c) __builtin_amdgcn_mfma_f32_16x16x32_bf16((a), (b), (c), 0, 0, 0)

__device__ __forceinline__ unsigned short f2bf(float f) {
    union { float f; unsigned u; } v; v.f = f;
    unsigned u = v.u + 0x7fffu + ((v.u >> 16) & 1u);   // round-to-nearest-even
    return (unsigned short)(u >> 16);
}

// XOR-swizzled LDS index helpers (ushort units). XOR hits bits 3..5 (16B slots),
// staying inside each logical row, so 16B ds_read_b128 alignment is preserved
// and 16 consecutive rows spread over 8 bank-slots (2-way = free).
__device__ __forceinline__ int kidx(int h, int d) { return (h * 256 + d) ^ ((h & 7) << 3); }  // K[64][256]
__device__ __forceinline__ int vidx(int d, int h) { return (d * 64 + h) ^ ((d & 7) << 3); }   // V^T[256][64]
__device__ __forceinline__ int widx(int q, int h) { return (q * 64 + h) ^ ((q & 7) << 3); }   // w[64][64]

__global__ __launch_bounds__(512, 4)
void maskattn_phase1(const float* __restrict__ Qg,
                     const float* __restrict__ Kg,
                     const float* __restrict__ Vg,
                     const float* __restrict__ Mg,
                     float* __restrict__ numW,
                     float* __restrict__ denW,
                     int CH, int C)
{
    __shared__ __attribute__((aligned(16))) unsigned short K_lds[64 * 256];   // 32 KB
    __shared__ __attribute__((aligned(16))) unsigned short V_lds[256 * 64];   // 32 KB, transposed [d][h]
    __shared__ __attribute__((aligned(16))) unsigned short w_lds[64 * 64];    // 8 KB (den aliased here)

    const int tid  = threadIdx.x;
    const int lane = tid & 63;
    const int wid  = tid >> 6;     // 0..7
    const int wq   = wid >> 1;     // 0..3 : owns q rows 16*wq..+15 (block-local)
    const int wn   = wid & 1;      // 0..1 : S h-half / PV d-half
    const int g    = lane >> 4;    // 0..3
    const int l15  = lane & 15;

    // XCD-aware mapping: the 8 q-tile blocks sharing one K/V chunk land on one XCD.
    const int bid = blockIdx.x;
    int qt, hc;
    if ((C & 7) == 0) {
        const int x = bid & 7;          // XCD (round-robin dispatch)
        const int r = bid >> 3;
        qt = r & 7;
        hc = x * (C >> 3) + (r >> 3);
    } else {
        qt = bid & 7;
        hc = bid >> 3;
    }
    const int qbase = qt * BQ;
    const long h0   = (long)hc * CH;
    const long hEnd = (h0 + CH < (long)NH) ? (h0 + CH) : (long)NH;

    // ---- Q fragments cached in registers: A[row=l15][k=8*g+i], d = 32*ks + 8*g + i ----
    short8 qa[8];
    {
        const float* qp = Qg + (size_t)(qbase + 16 * wq + l15) * DM + 8 * g;
#pragma unroll
        for (int ks = 0; ks < 8; ++ks) {
            floatx4 a = *(const floatx4*)(qp + 32 * ks);
            floatx4 b = *(const floatx4*)(qp + 32 * ks + 4);
            short8 fr;
            fr[0]=(short)f2bf(a[0]); fr[1]=(short)f2bf(a[1]);
            fr[2]=(short)f2bf(a[2]); fr[3]=(short)f2bf(a[3]);
            fr[4]=(short)f2bf(b[0]); fr[5]=(short)f2bf(b[1]);
            fr[6]=(short)f2bf(b[2]); fr[7]=(short)f2bf(b[3]);
            qa[ks] = fr;
        }
    }

    floatx4 acc[8];
#pragma unroll
    for (int i = 0; i < 8; ++i) {
        floatx4 z = {0.f, 0.f, 0.f, 0.f};
        acc[i] = z;
    }
    float dacc[4] = {0.f, 0.f, 0.f, 0.f};

    const int ntiles = (hEnd > h0) ? (int)((hEnd - h0 + BH - 1) / BH) : 0;

    for (int t = 0; t < ntiles; ++t) {
        const long hb = h0 + (long)t * BH;

        // ---- mask prefetch (C-frag layout, 64B-coalesced over l15) — overlaps staging ----
        float mreg[2][4];
#pragma unroll
        for (int fn = 0; fn < 2; ++fn) {
            const long h = hb + 32 * wn + 16 * fn + l15;
            const bool valid = (h < hEnd);
#pragma unroll
            for (int j = 0; j < 4; ++j) {
                mreg[fn][j] = valid ? Mg[(size_t)(qbase + 16 * wq + 4 * g + j) * NH + h] : 0.f;
            }
        }

        // ---- stage K tile: rows [hb..hb+63], f32 -> bf16, row-major swizzled ----
        {
            const int hr = tid >> 3;            // 0..63
            const int d0 = (tid & 7) * 4;
            long krow = hb + hr; if (krow > (long)NH - 1) krow = (long)NH - 1;
            const float* kp = Kg + (size_t)krow * DM;
#pragma unroll
            for (int c = 0; c < 8; ++c) {
                const int d = d0 + 32 * c;
                floatx4 v = *(const floatx4*)(kp + d);
                ushort4v p;
                p[0]=f2bf(v[0]); p[1]=f2bf(v[1]); p[2]=f2bf(v[2]); p[3]=f2bf(v[3]);
                *(ushort4v*)&K_lds[kidx(hr, d)] = p;
            }
        }
        // ---- stage V tile TRANSPOSED: V_lds[d][h], swizzled ----
        {
            const int dcol = tid & 63;
            const int hq0  = tid >> 6;          // 0..7
#pragma unroll
            for (int jh = 0; jh < 2; ++jh) {
                const int hq = hq0 + 8 * jh;    // 0..15 -> h rows 4*hq..+3
#pragma unroll
                for (int jd = 0; jd < 4; ++jd) {
                    const int d = dcol + 64 * jd;
                    ushort4v p;
#pragma unroll
                    for (int r = 0; r < 4; ++r) {
                        long hrow = hb + 4 * hq + r; if (hrow > (long)NH - 1) hrow = (long)NH - 1;
                        p[r] = f2bf(Vg[(size_t)hrow * DM + d]);
                    }
                    *(ushort4v*)&V_lds[vidx(d, 4 * hq)] = p;
                }
            }
        }
        __syncthreads();

        // ---- S = Q K^T : wave computes 16q x 32h at (16*wq, 32*wn) ----
        floatx4 sf[2];
        {
            floatx4 z = {0.f, 0.f, 0.f, 0.f};
            sf[0] = z; sf[1] = z;
        }
#pragma unroll
        for (int ks = 0; ks < 8; ++ks) {
            short8 kb0 = *(const short8*)&K_lds[kidx(32 * wn +      l15, 32 * ks + 8 * g)];
            short8 kb1 = *(const short8*)&K_lds[kidx(32 * wn + 16 + l15, 32 * ks + 8 * g)];
            sf[0] = MFMA_BF16(qa[ks], kb0, sf[0]);
            sf[1] = MFMA_BF16(qa[ks], kb1, sf[1]);
        }

        // ---- w = mask * exp(s/16) ----
#pragma unroll
        for (int fn = 0; fn < 2; ++fn) {
#pragma unroll
            for (int j = 0; j < 4; ++j) {
                const int rloc = 16 * wq + 4 * g + j;          // block-local q row
                float s = sf[fn][j] * 0.0625f;
                s = (s > 60.f) ? 60.f : s;                     // inf guard for clamped tail rows
                float w = mreg[fn][j] * __expf(s);
                dacc[j] += w;
                w_lds[widx(rloc, 32 * wn + 16 * fn + l15)] = f2bf(w);
            }
        }
        __syncthreads();

        // ---- PV: out(16q x 128d per wave) += w(.,64h) * V(64h, .) ----
#pragma unroll
        for (int ks = 0; ks < 2; ++ks) {
            short8 wa = *(const short8*)&w_lds[widx(16 * wq + l15, 32 * ks + 8 * g)];
#pragma unroll
            for (int fd = 0; fd < 8; ++fd) {
                short8 vb = *(const short8*)&V_lds[vidx(128 * wn + 16 * fd + l15, 32 * ks + 8 * g)];
                acc[fd] = MFMA_BF16(wa, vb, acc[fd]);
            }
        }
        __syncthreads();
    }

    // ---- den: reduce across the 16 lanes sharing a row; combine wn halves via LDS ----
    __syncthreads();
    float* dshare = (float*)w_lds;   // w_lds dead now; 512 B needed
#pragma unroll
    for (int j = 0; j < 4; ++j) {
        float v = dacc[j];
        v += __shfl_xor(v, 1);
        v += __shfl_xor(v, 2);
        v += __shfl_xor(v, 4);
        v += __shfl_xor(v, 8);
        if (l15 == 0) dshare[wn * 64 + 16 * wq + 4 * g + j] = v;
    }
    __syncthreads();
    if (tid < BQ) {
        denW[(size_t)hc * NQ + qbase + tid] = dshare[tid] + dshare[64 + tid];
    }

    // ---- num partial write ----
#pragma unroll
    for (int fd = 0; fd < 8; ++fd)
#pragma unroll
        for (int j = 0; j < 4; ++j) {
            const int qrow = qbase + 16 * wq + 4 * g + j;
            const int d    = 128 * wn + 16 * fd + l15;
            numW[((size_t)hc * NQ + qrow) * DM + d] = acc[fd][j];
        }
}

__global__ void maskattn_reduce(const float* __restrict__ numW,
                                const float* __restrict__ denW,
                                float* __restrict__ out, int C)
{
    const int q = blockIdx.x;
    const int d = threadIdx.x;
    float sn = 0.f, sd = 0.f;
    for (int c = 0; c < C; ++c) {
        sn += numW[((size_t)c * NQ + q) * DM + d];
        sd += denW[(size_t)c * NQ + q];
    }
    out[(size_t)q * DM + d] = sn / sd;
}

extern "C" void kernel_launch(void* const* d_in, const int* in_sizes, int n_in,
                              void* d_out, int out_size, void* d_ws, size_t ws_size,
                              hipStream_t stream)
{
    const float* Qg = (const float*)d_in[0];
    const float* Kg = (const float*)d_in[1];
    const float* Vg = (const float*)d_in[2];
    const float* Mg = (const float*)d_in[3];
    float* out = (float*)d_out;

    const size_t per_chunk = (size_t)NQ * DM * sizeof(float) + (size_t)NQ * sizeof(float);
    int C = (int)(ws_size / per_chunk);
    if (C > 64) C = 64;
    float* numW;
    float* denW;
    if (C >= 1) {
        numW = (float*)d_ws;
        denW = numW + (size_t)C * NQ * DM;
    } else {
        C = 1;
        numW = out;                  // emergency fallback
        denW = (float*)d_ws;
    }
    const int ch64 = (NH + 64 * C - 1) / (64 * C);
    const int CH = 64 * ch64;

    maskattn_phase1<<<dim3((NQ / BQ) * C), dim3(512), 0, stream>>>(Qg, Kg, Vg, Mg, numW, denW, CH, C);
    maskattn_reduce<<<dim3(NQ), dim3(DM), 0, stream>>>(numW, denW, out, C);
}